// Round 3
// baseline (172.312 us; speedup 1.0000x reference)
//
#include <hip/hip_runtime.h>
#include <stdint.h>
#include <type_traits>

#define M_DIM 16384
#define N_DIM 2048
#define K_DIM 2048

typedef __bf16 bf16_t;
typedef __bf16 bf16x8 __attribute__((ext_vector_type(8)));
typedef __bf16 bf16x4 __attribute__((ext_vector_type(4)));
typedef float f32x4 __attribute__((ext_vector_type(4)));
typedef float f32x16 __attribute__((ext_vector_type(16)));

template <int N> using ic = std::integral_constant<int, N>;

__device__ __forceinline__ void gload_lds16(const void* g, void* l) {
  __builtin_amdgcn_global_load_lds(
      (const __attribute__((address_space(1))) void*)g,
      (__attribute__((address_space(3))) void*)l, 16, 0, 0);
}

// float -> bf16 (RNE). SIGN applies sign() first (exact in bf16).
template <bool SIGN>
__global__ void cvt_kernel(const float* __restrict__ in, bf16_t* __restrict__ out) {
  long long i = ((long long)blockIdx.x * 256 + threadIdx.x) * 8;
  const float4* p = (const float4*)(in + i);
  float4 v0 = p[0];
  float4 v1 = p[1];
  float f[8] = {v0.x, v0.y, v0.z, v0.w, v1.x, v1.y, v1.z, v1.w};
  bf16x8 r;
#pragma unroll
  for (int j = 0; j < 8; ++j) {
    float v = f[j];
    if (SIGN) v = (v > 0.f) ? 1.f : ((v < 0.f) ? -1.f : 0.f);
    r[j] = (bf16_t)v;
  }
  *(bf16x8*)(out + i) = r;
}

// ============================================================================
// 256x256 tile, BK=32, 8 waves (2m x 4n), 4-slot LDS ring, 2 phases per K-tile.
// Round-2 verified sync schedule (barriers / vmcnt(8|4|0) / stage order)
// unchanged. Round-3 changes: (a) all LDS frag addresses + global stage
// addresses precomputed once; t-loop unrolled x4 so slot offsets are DS-imm
// constants; (b) MFMA shape 16x16x32 -> 32x32x16 (half the instructions,
// 2495 vs 2176 TF ceiling). Swizzle phys_col = col ^ (((row>>1)&3)<<4),
// applied on pre-swizzled global source + ds_read addr (rule #21).
// ============================================================================
__global__ __launch_bounds__(512, 2) void gemm32(const bf16_t* __restrict__ A,
                                                 const bf16_t* __restrict__ B,
                                                 const float* __restrict__ alpha_p,
                                                 float* __restrict__ C) {
  extern __shared__ char smem[];
  char* AsB = smem;             // 4 slots x 16 KiB (256x32 bf16)
  char* BsB = smem + 65536;

  const int tid = threadIdx.x;
  const int lane = tid & 63;
  const int wid = tid >> 6;
  const int wm = wid >> 2;   // 0..1 -> rows wm*128..+127
  const int wn = wid & 3;    // 0..3 -> cols wn*64..+63

  // XCD-aware bijective swizzle (512 blocks, 512 % 8 == 0)
  const int bid = blockIdx.x;
  const int swz = (bid & 7) * 64 + (bid >> 3);
  const int bm = swz >> 3;   // 0..63
  const int bn = swz & 7;    // 0..7

  const int rl = lane & 31;  // 32x32 frag row
  const int kh = lane >> 5;  // k-half (8 bf16)

  // ---- Precomputed fragment LDS pointers (slot 0; + slot*16384 as DS imm) ----
  const char* apc[4][2];  // [mt][k2]
  const char* bpc[2][2];  // [nt][k2]
#pragma unroll
  for (int mt = 0; mt < 4; ++mt)
#pragma unroll
    for (int k2 = 0; k2 < 2; ++k2) {
      int row = wm * 128 + mt * 32 + rl;
      int c2 = k2 * 32 + kh * 16;
      apc[mt][k2] = AsB + row * 64 + (c2 ^ (((row >> 1) & 3) << 4));
    }
#pragma unroll
  for (int nt = 0; nt < 2; ++nt)
#pragma unroll
    for (int k2 = 0; k2 < 2; ++k2) {
      int row = wn * 64 + nt * 32 + rl;
      int c2 = k2 * 32 + kh * 16;
      bpc[nt][k2] = BsB + row * 64 + (c2 ^ (((row >> 1) & 3) << 4));
    }

  // ---- Precomputed stage pointers (tile 0). Source pre-swizzled so the
  //      linear gload_lds dest yields swizzled LDS (round-2 verified). ----
  const char* asrc[2];
  const char* bsrc[2];
  char* aldst[2];
  char* bldst[2];
#pragma unroll
  for (int q = 0; q < 2; ++q) {
    int P = q * 8192 + tid * 16;                     // phys byte in 16KB slot
    int row = P >> 6;                                // 0..255
    int lcol = (P & 63) ^ (((row >> 1) & 3) << 4);   // logical byte-in-row
    asrc[q] = (const char*)(A + (size_t)(bm * 256 + row) * K_DIM) + lcol;
    bsrc[q] = (const char*)(B + (size_t)(bn * 256 + row) * K_DIM) + lcol;
    aldst[q] = AsB + q * 8192 + wid * 1024;          // wave-uniform
    bldst[q] = BsB + q * 8192 + wid * 1024;
  }

  f32x16 acc[4][2];
#pragma unroll
  for (int mt = 0; mt < 4; ++mt)
#pragma unroll
    for (int nt = 0; nt < 2; ++nt)
#pragma unroll
      for (int r = 0; r < 16; ++r) acc[mt][nt][r] = 0.f;

  // ---- Prologue: stage tiles 0,1,2; wait tile 0 (8 younger in flight) ----
#pragma unroll
  for (int tt = 0; tt < 3; ++tt) {
    gload_lds16(asrc[0] + tt * 64, aldst[0] + tt * 16384);
    gload_lds16(asrc[1] + tt * 64, aldst[1] + tt * 16384);
    gload_lds16(bsrc[0] + tt * 64, bldst[0] + tt * 16384);
    gload_lds16(bsrc[1] + tt * 64, bldst[1] + tt * 16384);
  }
  asm volatile("s_waitcnt vmcnt(8)" ::: "memory");
  __builtin_amdgcn_s_barrier();

  // One K-tile (BK=32, 2 phases). U = t&3 (compile-time). MODE: 0 = stage
  // tile t+3 + vmcnt(8); 1 = no stage, vmcnt(4); 2 = no stage, vmcnt(0).
  auto kstep = [&](auto UC, auto MC) {
    constexpr int U = UC.value;
    constexpr int MODE = MC.value;
    constexpr int SLOT = U * 16384;
    constexpr int PSLOT = ((U + 3) & 3) * 16384;
    constexpr int GOFF = (U + 3) * 64;

    // ---- Phase A: a(mt0-1) + all b; stage A(t+3); MFMA mt0-1 ----
    bf16x8 a01[2][2], b[2][2];
#pragma unroll
    for (int mt = 0; mt < 2; ++mt)
#pragma unroll
      for (int k2 = 0; k2 < 2; ++k2)
        a01[mt][k2] = *(const bf16x8*)(apc[mt][k2] + SLOT);
#pragma unroll
    for (int nt = 0; nt < 2; ++nt)
#pragma unroll
      for (int k2 = 0; k2 < 2; ++k2)
        b[nt][k2] = *(const bf16x8*)(bpc[nt][k2] + SLOT);
    if constexpr (MODE == 0) {
      gload_lds16(asrc[0] + GOFF, aldst[0] + PSLOT);
      gload_lds16(asrc[1] + GOFF, aldst[1] + PSLOT);
    }
    __builtin_amdgcn_s_barrier();
    asm volatile("s_waitcnt lgkmcnt(0)" ::: "memory");
    __builtin_amdgcn_s_setprio(1);
#pragma unroll
    for (int k2 = 0; k2 < 2; ++k2)
#pragma unroll
      for (int mt = 0; mt < 2; ++mt)
#pragma unroll
        for (int nt = 0; nt < 2; ++nt)
          acc[mt][nt] = __builtin_amdgcn_mfma_f32_32x32x16_bf16(
              a01[mt][k2], b[nt][k2], acc[mt][nt], 0, 0, 0);
    __builtin_amdgcn_s_setprio(0);
    __builtin_amdgcn_s_barrier();

    // ---- Phase B: a(mt2-3), b reused; stage B(t+3); vmcnt; MFMA mt2-3 ----
    bf16x8 a23[2][2];
#pragma unroll
    for (int mt = 0; mt < 2; ++mt)
#pragma unroll
      for (int k2 = 0; k2 < 2; ++k2)
        a23[mt][k2] = *(const bf16x8*)(apc[2 + mt][k2] + SLOT);
    if constexpr (MODE == 0) {
      gload_lds16(bsrc[0] + GOFF, bldst[0] + PSLOT);
      gload_lds16(bsrc[1] + GOFF, bldst[1] + PSLOT);
      asm volatile("s_waitcnt vmcnt(8)" ::: "memory");   // t+2,t+3 in flight
    } else if constexpr (MODE == 1) {
      asm volatile("s_waitcnt vmcnt(4)" ::: "memory");   // tile 63 in flight
    } else {
      asm volatile("s_waitcnt vmcnt(0)" ::: "memory");
    }
    __builtin_amdgcn_s_barrier();
    asm volatile("s_waitcnt lgkmcnt(0)" ::: "memory");
    __builtin_amdgcn_s_setprio(1);
#pragma unroll
    for (int k2 = 0; k2 < 2; ++k2)
#pragma unroll
      for (int mt = 0; mt < 2; ++mt)
#pragma unroll
        for (int nt = 0; nt < 2; ++nt)
          acc[2 + mt][nt] = __builtin_amdgcn_mfma_f32_32x32x16_bf16(
              a23[mt][k2], b[nt][k2], acc[2 + mt][nt], 0, 0, 0);
    __builtin_amdgcn_s_setprio(0);
    __builtin_amdgcn_s_barrier();
  };

#pragma unroll 1
  for (int T = 0; T < 15; ++T) {
    kstep(ic<0>{}, ic<0>{});
    kstep(ic<1>{}, ic<0>{});
    kstep(ic<2>{}, ic<0>{});
    kstep(ic<3>{}, ic<0>{});
    asrc[0] += 256; asrc[1] += 256; bsrc[0] += 256; bsrc[1] += 256;
  }
  // Tail: t = 60..63 (stage tile 63 at t=60; drain vmcnt 8 -> 4 -> 0)
  kstep(ic<0>{}, ic<0>{});
  kstep(ic<1>{}, ic<1>{});
  kstep(ic<2>{}, ic<2>{});
  kstep(ic<3>{}, ic<2>{});

  // ---- Epilogue: 32x32 C/D layout col=lane&31, row=(reg&3)+8*(reg>>2)+4*kh
  //      (m74/m101-verified). ----
  const float alpha = alpha_p[0];
  const int rbase = bm * 256 + wm * 128;
  const int cbase = bn * 256 + wn * 64 + rl;
#pragma unroll
  for (int mt = 0; mt < 4; ++mt)
#pragma unroll
    for (int nt = 0; nt < 2; ++nt)
#pragma unroll
      for (int r = 0; r < 16; ++r) {
        int rr = (r & 3) + 8 * (r >> 2) + 4 * kh;
        C[(size_t)(rbase + mt * 32 + rr) * N_DIM + cbase + nt * 32] =
            alpha * acc[mt][nt][r];
      }
}

// ---- Workspace-free fallback (round-1 verified structure, f32 reg-staged) ----
__global__ __launch_bounds__(256) void gemm_fallback(const float* __restrict__ Ap,
                                                     const float* __restrict__ Bp,
                                                     const float* __restrict__ alpha_p,
                                                     float* __restrict__ C) {
  __shared__ bf16_t Asf[128 * 32];
  __shared__ bf16_t Bsf[128 * 32];
  const int tid = threadIdx.x;
  const int lane = tid & 63;
  const int wid = tid >> 6;
  const int wr = wid >> 1;
  const int wc = wid & 1;
  const int cpx = gridDim.x >> 3;
  const int bid = blockIdx.x;
  const int swz = (bid & 7) * cpx + (bid >> 3);
  const int NB = N_DIM / 128;
  const int bm = swz / NB;
  const int bn = swz % NB;
  f32x4 acc[4][4];
#pragma unroll
  for (int m = 0; m < 4; ++m)
#pragma unroll
    for (int n = 0; n < 4; ++n) acc[m][n] = (f32x4){0.f, 0.f, 0.f, 0.f};
  const int r0 = lane & 15;
  const int ko = (lane >> 4) * 8;
  for (int kk = 0; kk < K_DIM; kk += 32) {
    const float* Af = Ap + (size_t)bm * 128 * K_DIM + kk;
    const float* Bf = Bp + (size_t)bn * 128 * K_DIM + kk;
#pragma unroll
    for (int q = 0; q < 4; ++q) {
      int e = q * 256 + tid;
      int row = e >> 3;
      int kc = (e & 7) << 2;
      float4 v = *(const float4*)(Af + (size_t)row * K_DIM + kc);
      bf16x4 tv;
      tv[0] = (bf16_t)v.x; tv[1] = (bf16_t)v.y; tv[2] = (bf16_t)v.z; tv[3] = (bf16_t)v.w;
      *(bf16x4*)&Asf[e * 4] = tv;
    }
#pragma unroll
    for (int q = 0; q < 4; ++q) {
      int e = q * 256 + tid;
      int row = e >> 3;
      int kc = (e & 7) << 2;
      float4 v = *(const float4*)(Bf + (size_t)row * K_DIM + kc);
      float s[4] = {v.x, v.y, v.z, v.w};
      bf16x4 tv;
#pragma unroll
      for (int j = 0; j < 4; ++j)
        tv[j] = (bf16_t)((s[j] > 0.f) ? 1.f : ((s[j] < 0.f) ? -1.f : 0.f));
      *(bf16x4*)&Bsf[e * 4] = tv;
    }
    __syncthreads();
    bf16x8 a[4], b[4];
#pragma unroll
    for (int m = 0; m < 4; ++m) a[m] = *(const bf16x8*)&Asf[(wr * 64 + m * 16 + r0) * 32 + ko];
#pragma unroll
    for (int n = 0; n < 4; ++n) b[n] = *(const bf16x8*)&Bsf[(wc * 64 + n * 16 + r0) * 32 + ko];
#pragma unroll
    for (int m = 0; m < 4; ++m)
#pragma unroll
      for (int n = 0; n < 4; ++n)
        acc[m][n] = __builtin_amdgcn_mfma_f32_16x16x32_bf16(a[m], b[n], acc[m][n], 0, 0, 0);
    __syncthreads();
  }
  const float alpha = alpha_p[0];
  const int rowb = bm * 128 + wr * 64 + (lane >> 4) * 4;
  const int colb = bn * 128 + wc * 64 + r0;
#pragma unroll
  for (int m = 0; m < 4; ++m)
#pragma unroll
    for (int n = 0; n < 4; ++n)
#pragma unroll
      for (int r = 0; r < 4; ++r)
        C[(size_t)(rowb + m * 16 + r) * N_DIM + colb + n * 16] = alpha * acc[m][n][r];
}

extern "C" void kernel_launch(void* const* d_in, const int* in_sizes, int n_in,
                              void* d_out, int out_size, void* d_ws, size_t ws_size,
                              hipStream_t stream) {
  const float* x = (const float*)d_in[0];
  const float* w = (const float*)d_in[1];
  const float* alpha = (const float*)d_in[2];
  float* out = (float*)d_out;

  const size_t nx = (size_t)M_DIM * K_DIM;
  const size_t nw = (size_t)N_DIM * K_DIM;
  const size_t need = (nx + nw) * sizeof(bf16_t);

  if (ws_size >= need) {
    bf16_t* xb = (bf16_t*)d_ws;
    bf16_t* wb = xb + nx;
    cvt_kernel<false><<<(int)(nx / 2048), 256, 0, stream>>>(x, xb);
    cvt_kernel<true><<<(int)(nw / 2048), 256, 0, stream>>>(w, wb);
    (void)hipFuncSetAttribute((const void*)gemm32,
                              hipFuncAttributeMaxDynamicSharedMemorySize, 131072);
    gemm32<<<512, 512, 131072, stream>>>(xb, wb, alpha, out);
  } else {
    gemm_fallback<<<(M_DIM / 128) * (N_DIM / 128), 256, 0, stream>>>(x, w, alpha, out);
  }
}

// Round 4
// 171.558 us; speedup vs baseline: 1.0044x; 1.0044x over previous
//
#include <hip/hip_runtime.h>
#include <stdint.h>
#include <type_traits>

#define M_DIM 16384
#define N_DIM 2048
#define K_DIM 2048

typedef __bf16 bf16_t;
typedef __bf16 bf16x8 __attribute__((ext_vector_type(8)));
typedef __bf16 bf16x4 __attribute__((ext_vector_type(4)));
typedef float f32x4 __attribute__((ext_vector_type(4)));
typedef float f32x16 __attribute__((ext_vector_type(16)));

template <int N> using ic = std::integral_constant<int, N>;

__device__ __forceinline__ void gload_lds16(const void* g, void* l) {
  __builtin_amdgcn_global_load_lds(
      (const __attribute__((address_space(1))) void*)g,
      (__attribute__((address_space(3))) void*)l, 16, 0, 0);
}

// float -> bf16 (RNE). SIGN applies sign() first (exact in bf16).
template <bool SIGN>
__global__ void cvt_kernel(const float* __restrict__ in, bf16_t* __restrict__ out) {
  long long i = ((long long)blockIdx.x * 256 + threadIdx.x) * 8;
  const float4* p = (const float4*)(in + i);
  float4 v0 = p[0];
  float4 v1 = p[1];
  float f[8] = {v0.x, v0.y, v0.z, v0.w, v1.x, v1.y, v1.z, v1.w};
  bf16x8 r;
#pragma unroll
  for (int j = 0; j < 8; ++j) {
    float v = f[j];
    if (SIGN) v = (v > 0.f) ? 1.f : ((v < 0.f) ? -1.f : 0.f);
    r[j] = (bf16_t)v;
  }
  *(bf16x8*)(out + i) = r;
}

// ============================================================================
// 256x256 tile, BK=32, 8 waves (2m x 4n), 4-slot LDS ring. Round-2/3 verified
// sync skeleton (stage t+3 during t; vmcnt(8|4|0)+barrier collective-landing).
// Round-4 changes:
//  (a) Register-pipelined fragment reads: P1 issues a23(t) then MFMAs
//      a01(t)xb(t) (loaded during t-1 P2); P2 issues a01(t+1)+b(t+1) (legal:
//      after the vmcnt(8)+barrier guaranteeing slot t+1) then MFMAs a23(t)xb(t).
//      Compiler emits minimal counted lgkmcnt from SSA deps -> LDS overlaps MFMA.
//  (b) Conflict-free 32x32 frag LDS layout, per 32-row sub-block (2 KiB):
//      addr(row,k2,kh) = sb*2048 + k2*1024 + (row&15)*64
//                        + (((row>>4)<<5 | kh<<4) ^ (((row>>1)&3)<<4))
//      -> each (mt,k2) wave read = full contiguous 1 KiB (16 rows x 4 cols),
//      the round-2 zero-conflict shape. Staging: linear gload_lds dest +
//      inverse-permuted global source (both-sides rule).
// ============================================================================
__global__ __launch_bounds__(512, 2) void gemm32(const bf16_t* __restrict__ A,
                                                 const bf16_t* __restrict__ B,
                                                 const float* __restrict__ alpha_p,
                                                 float* __restrict__ C) {
  extern __shared__ char smem[];
  char* AsB = smem;             // 4 slots x 16 KiB
  char* BsB = smem + 65536;

  const int tid = threadIdx.x;
  const int lane = tid & 63;
  const int wid = tid >> 6;
  const int wm = wid >> 2;   // 0..1 -> rows wm*128..+127
  const int wn = wid & 3;    // 0..3 -> cols wn*64..+63

  // XCD-aware bijective swizzle (512 blocks, 512 % 8 == 0)
  const int bid = blockIdx.x;
  const int swz = (bid & 7) * 64 + (bid >> 3);
  const int bm = swz >> 3;   // 0..63
  const int bn = swz & 7;    // 0..7

  const int rl = lane & 31;  // 32x32 frag row
  const int kh = lane >> 5;  // k-half (8 bf16)

  // ---- Fragment LDS pointers (slot 0), permuted-layout formula ----
  const char* apc[4][2];  // [mt][k2]
  const char* bpc[2][2];  // [nt][k2]
  {
    const int r15 = rl & 15;
    const int rhi = rl >> 4;
    const int swc = ((rhi << 5) | (kh << 4)) ^ (((r15 >> 1) & 3) << 4);
#pragma unroll
    for (int mt = 0; mt < 4; ++mt)
#pragma unroll
      for (int k2 = 0; k2 < 2; ++k2)
        apc[mt][k2] = AsB + (wm * 4 + mt) * 2048 + k2 * 1024 + r15 * 64 + swc;
#pragma unroll
    for (int nt = 0; nt < 2; ++nt)
#pragma unroll
      for (int k2 = 0; k2 < 2; ++k2)
        bpc[nt][k2] = BsB + (wn * 2 + nt) * 2048 + k2 * 1024 + r15 * 64 + swc;
  }

  // ---- Stage pointers (tile 0): inverse-permuted global source, linear dest ----
  const char* asrc[2];
  const char* bsrc[2];
  char* aldst[2];
  char* bldst[2];
#pragma unroll
  for (int q = 0; q < 2; ++q) {
    int P = q * 8192 + tid * 16;   // phys byte in 16KB slot
    int sb = P >> 11;              // 32-row sub-block
    int p11 = P & 2047;
    int k2 = p11 >> 10;
    int r15 = (p11 >> 6) & 15;
    int c = p11 & 63;              // multiple of 16
    int un = c ^ (((r15 >> 1) & 3) << 4);
    int rhi = un >> 5;
    int khh = (un >> 4) & 1;
    int row = sb * 32 + rhi * 16 + r15;
    int kb = k2 * 32 + khh * 16;   // byte offset within 64B K-tile row
    asrc[q] = (const char*)A + (size_t)(bm * 256 + row) * (K_DIM * 2) + kb;
    bsrc[q] = (const char*)B + (size_t)(bn * 256 + row) * (K_DIM * 2) + kb;
    aldst[q] = AsB + q * 8192 + wid * 1024;   // wave-uniform linear
    bldst[q] = BsB + q * 8192 + wid * 1024;
  }

  f32x16 acc[4][2];
#pragma unroll
  for (int mt = 0; mt < 4; ++mt)
#pragma unroll
    for (int nt = 0; nt < 2; ++nt)
#pragma unroll
      for (int r = 0; r < 16; ++r) acc[mt][nt][r] = 0.f;

  // Persistent register fragments
  bf16x8 a01[2][2], a23[2][2], bfr[2][2][2];  // bfr[parity][nt][k2]

  // ---- Prologue: stage tiles 0,1,2; wait tile 0; preload a01(0), b(0) ----
#pragma unroll
  for (int tt = 0; tt < 3; ++tt) {
    gload_lds16(asrc[0] + tt * 64, aldst[0] + tt * 16384);
    gload_lds16(asrc[1] + tt * 64, aldst[1] + tt * 16384);
    gload_lds16(bsrc[0] + tt * 64, bldst[0] + tt * 16384);
    gload_lds16(bsrc[1] + tt * 64, bldst[1] + tt * 16384);
  }
  asm volatile("s_waitcnt vmcnt(8)" ::: "memory");
  __builtin_amdgcn_s_barrier();
#pragma unroll
  for (int mt = 0; mt < 2; ++mt)
#pragma unroll
    for (int k2 = 0; k2 < 2; ++k2)
      a01[mt][k2] = *(const bf16x8*)(apc[mt][k2]);
#pragma unroll
  for (int nt = 0; nt < 2; ++nt)
#pragma unroll
    for (int k2 = 0; k2 < 2; ++k2)
      bfr[0][nt][k2] = *(const bf16x8*)(bpc[nt][k2]);

  // One K-tile. U = t&3 (compile-time). MODE: 0 = stage t+3, vmcnt(8);
  // 1 = vmcnt(4); 2 = vmcnt(0); 3 = tail (no vmcnt, no next-tile reads).
  auto kstep = [&](auto UC, auto MC) {
    constexpr int U = UC.value;
    constexpr int MODE = MC.value;
    constexpr int SLOT = U * 16384;
    constexpr int NSLOT = ((U + 1) & 3) * 16384;
    constexpr int PSLOT = ((U + 3) & 3) * 16384;
    constexpr int GOFF = (U + 3) * 64;
    constexpr int PAR = U & 1;

    // ---- P1: issue a23(t); stage t+3; MFMA a01 x b; vmcnt; barrier ----
#pragma unroll
    for (int mt = 0; mt < 2; ++mt)
#pragma unroll
      for (int k2 = 0; k2 < 2; ++k2)
        a23[mt][k2] = *(const bf16x8*)(apc[2 + mt][k2] + SLOT);
    if constexpr (MODE == 0) {
      gload_lds16(asrc[0] + GOFF, aldst[0] + PSLOT);
      gload_lds16(asrc[1] + GOFF, aldst[1] + PSLOT);
      gload_lds16(bsrc[0] + GOFF, bldst[0] + PSLOT);
      gload_lds16(bsrc[1] + GOFF, bldst[1] + PSLOT);
    }
    __builtin_amdgcn_s_setprio(1);
#pragma unroll
    for (int k2 = 0; k2 < 2; ++k2)
#pragma unroll
      for (int mt = 0; mt < 2; ++mt)
#pragma unroll
        for (int nt = 0; nt < 2; ++nt)
          acc[mt][nt] = __builtin_amdgcn_mfma_f32_32x32x16_bf16(
              a01[mt][k2], bfr[PAR][nt][k2], acc[mt][nt], 0, 0, 0);
    __builtin_amdgcn_s_setprio(0);
    if constexpr (MODE == 0) {
      asm volatile("s_waitcnt vmcnt(8)" ::: "memory");   // tile t+1 landed
    } else if constexpr (MODE == 1) {
      asm volatile("s_waitcnt vmcnt(4)" ::: "memory");
    } else if constexpr (MODE == 2) {
      asm volatile("s_waitcnt vmcnt(0)" ::: "memory");
    }
    __builtin_amdgcn_s_barrier();   // slot t+1 valid collectively

    // ---- P2: issue a01(t+1)+b(t+1); MFMA a23 x b; barrier ----
    if constexpr (MODE != 3) {
#pragma unroll
      for (int mt = 0; mt < 2; ++mt)
#pragma unroll
        for (int k2 = 0; k2 < 2; ++k2)
          a01[mt][k2] = *(const bf16x8*)(apc[mt][k2] + NSLOT);
#pragma unroll
      for (int nt = 0; nt < 2; ++nt)
#pragma unroll
        for (int k2 = 0; k2 < 2; ++k2)
          bfr[PAR ^ 1][nt][k2] = *(const bf16x8*)(bpc[nt][k2] + NSLOT);
    }
    __builtin_amdgcn_s_setprio(1);
#pragma unroll
    for (int k2 = 0; k2 < 2; ++k2)
#pragma unroll
      for (int mt = 0; mt < 2; ++mt)
#pragma unroll
        for (int nt = 0; nt < 2; ++nt)
          acc[2 + mt][nt] = __builtin_amdgcn_mfma_f32_32x32x16_bf16(
              a23[mt][k2], bfr[PAR][nt][k2], acc[2 + mt][nt], 0, 0, 0);
    __builtin_amdgcn_s_setprio(0);
    __builtin_amdgcn_s_barrier();   // all slot-t readers done before next stage
  };

#pragma unroll 1
  for (int T = 0; T < 15; ++T) {
    kstep(ic<0>{}, ic<0>{});
    kstep(ic<1>{}, ic<0>{});
    kstep(ic<2>{}, ic<0>{});
    kstep(ic<3>{}, ic<0>{});
    asrc[0] += 256; asrc[1] += 256; bsrc[0] += 256; bsrc[1] += 256;
  }
  kstep(ic<0>{}, ic<0>{});   // tile 60 (stages 63)
  kstep(ic<1>{}, ic<1>{});   // tile 61
  kstep(ic<2>{}, ic<2>{});   // tile 62
  kstep(ic<3>{}, ic<3>{});   // tile 63

  // ---- Epilogue: 32x32 C/D layout col=lane&31, row=(r&3)+8*(r>>2)+4*kh ----
  const float alpha = alpha_p[0];
  const int rbase = bm * 256 + wm * 128;
  const int cbase = bn * 256 + wn * 64 + rl;
#pragma unroll
  for (int mt = 0; mt < 4; ++mt)
#pragma unroll
    for (int nt = 0; nt < 2; ++nt)
#pragma unroll
      for (int r = 0; r < 16; ++r) {
        int rr = (r & 3) + 8 * (r >> 2) + 4 * kh;
        C[(size_t)(rbase + mt * 32 + rr) * N_DIM + cbase + nt * 32] =
            alpha * acc[mt][nt][r];
      }
}

// ---- Workspace-free fallback (round-1 verified structure, f32 reg-staged) ----
__global__ __launch_bounds__(256) void gemm_fallback(const float* __restrict__ Ap,
                                                     const float* __restrict__ Bp,
                                                     const float* __restrict__ alpha_p,
                                                     float* __restrict__ C) {
  __shared__ bf16_t Asf[128 * 32];
  __shared__ bf16_t Bsf[128 * 32];
  const int tid = threadIdx.x;
  const int lane = tid & 63;
  const int wid = tid >> 6;
  const int wr = wid >> 1;
  const int wc = wid & 1;
  const int cpx = gridDim.x >> 3;
  const int bid = blockIdx.x;
  const int swz = (bid & 7) * cpx + (bid >> 3);
  const int NB = N_DIM / 128;
  const int bm = swz / NB;
  const int bn = swz % NB;
  f32x4 acc[4][4];
#pragma unroll
  for (int m = 0; m < 4; ++m)
#pragma unroll
    for (int n = 0; n < 4; ++n) acc[m][n] = (f32x4){0.f, 0.f, 0.f, 0.f};
  const int r0 = lane & 15;
  const int ko = (lane >> 4) * 8;
  for (int kk = 0; kk < K_DIM; kk += 32) {
    const float* Af = Ap + (size_t)bm * 128 * K_DIM + kk;
    const float* Bf = Bp + (size_t)bn * 128 * K_DIM + kk;
#pragma unroll
    for (int q = 0; q < 4; ++q) {
      int e = q * 256 + tid;
      int row = e >> 3;
      int kc = (e & 7) << 2;
      float4 v = *(const float4*)(Af + (size_t)row * K_DIM + kc);
      bf16x4 tv;
      tv[0] = (bf16_t)v.x; tv[1] = (bf16_t)v.y; tv[2] = (bf16_t)v.z; tv[3] = (bf16_t)v.w;
      *(bf16x4*)&Asf[e * 4] = tv;
    }
#pragma unroll
    for (int q = 0; q < 4; ++q) {
      int e = q * 256 + tid;
      int row = e >> 3;
      int kc = (e & 7) << 2;
      float4 v = *(const float4*)(Bf + (size_t)row * K_DIM + kc);
      float s[4] = {v.x, v.y, v.z, v.w};
      bf16x4 tv;
#pragma unroll
      for (int j = 0; j < 4; ++j)
        tv[j] = (bf16_t)((s[j] > 0.f) ? 1.f : ((s[j] < 0.f) ? -1.f : 0.f));
      *(bf16x4*)&Bsf[e * 4] = tv;
    }
    __syncthreads();
    bf16x8 a[4], b[4];
#pragma unroll
    for (int m = 0; m < 4; ++m) a[m] = *(const bf16x8*)&Asf[(wr * 64 + m * 16 + r0) * 32 + ko];
#pragma unroll
    for (int n = 0; n < 4; ++n) b[n] = *(const bf16x8*)&Bsf[(wc * 64 + n * 16 + r0) * 32 + ko];
#pragma unroll
    for (int m = 0; m < 4; ++m)
#pragma unroll
      for (int n = 0; n < 4; ++n)
        acc[m][n] = __builtin_amdgcn_mfma_f32_16x16x32_bf16(a[m], b[n], acc[m][n], 0, 0, 0);
    __syncthreads();
  }
  const float alpha = alpha_p[0];
  const int rowb = bm * 128 + wr * 64 + (lane >> 4) * 4;
  const int colb = bn * 128 + wc * 64 + r0;
#pragma unroll
  for (int m = 0; m < 4; ++m)
#pragma unroll
    for (int n = 0; n < 4; ++n)
#pragma unroll
      for (int r = 0; r < 4; ++r)
        C[(size_t)(rowb + m * 16 + r) * N_DIM + colb + n * 16] = alpha * acc[m][n][r];
}

extern "C" void kernel_launch(void* const* d_in, const int* in_sizes, int n_in,
                              void* d_out, int out_size, void* d_ws, size_t ws_size,
                              hipStream_t stream) {
  const float* x = (const float*)d_in[0];
  const float* w = (const float*)d_in[1];
  const float* alpha = (const float*)d_in[2];
  float* out = (float*)d_out;

  const size_t nx = (size_t)M_DIM * K_DIM;
  const size_t nw = (size_t)N_DIM * K_DIM;
  const size_t need = (nx + nw) * sizeof(bf16_t);

  if (ws_size >= need) {
    bf16_t* xb = (bf16_t*)d_ws;
    bf16_t* wb = xb + nx;
    cvt_kernel<false><<<(int)(nx / 2048), 256, 0, stream>>>(x, xb);
    cvt_kernel<true><<<(int)(nw / 2048), 256, 0, stream>>>(w, wb);
    (void)hipFuncSetAttribute((const void*)gemm32,
                              hipFuncAttributeMaxDynamicSharedMemorySize, 131072);
    gemm32<<<512, 512, 131072, stream>>>(xb, wb, alpha, out);
  } else {
    gemm_fallback<<<(M_DIM / 128) * (N_DIM / 128), 256, 0, stream>>>(x, w, alpha, out);
  }
}

// Round 5
// 168.479 us; speedup vs baseline: 1.0228x; 1.0183x over previous
//
#include <hip/hip_runtime.h>
#include <stdint.h>
#include <type_traits>

#define M_DIM 16384
#define N_DIM 2048
#define K_DIM 2048

typedef __bf16 bf16_t;
typedef __bf16 bf16x8 __attribute__((ext_vector_type(8)));
typedef __bf16 bf16x4 __attribute__((ext_vector_type(4)));
typedef float f32x4 __attribute__((ext_vector_type(4)));

template <int N> using ic = std::integral_constant<int, N>;

__device__ __forceinline__ void gload_lds16(const void* g, void* l) {
  __builtin_amdgcn_global_load_lds(
      (const __attribute__((address_space(1))) void*)g,
      (__attribute__((address_space(3))) void*)l, 16, 0, 0);
}

// float -> bf16 (RNE). SIGN applies sign() first (exact in bf16).
template <bool SIGN>
__global__ void cvt_kernel(const float* __restrict__ in, bf16_t* __restrict__ out) {
  long long i = ((long long)blockIdx.x * 256 + threadIdx.x) * 8;
  const float4* p = (const float4*)(in + i);
  float4 v0 = p[0];
  float4 v1 = p[1];
  float f[8] = {v0.x, v0.y, v0.z, v0.w, v1.x, v1.y, v1.z, v1.w};
  bf16x8 r;
#pragma unroll
  for (int j = 0; j < 8; ++j) {
    float v = f[j];
    if (SIGN) v = (v > 0.f) ? 1.f : ((v < 0.f) ? -1.f : 0.f);
    r[j] = (bf16_t)v;
  }
  *(bf16x8*)(out + i) = r;
}

// ============================================================================
// m201-template port: 256x256 tile, BK=64, 8 waves (2Mx4N, 128x64/wave),
// 2-buffer LDS (2x64KB), 4 phases/K-tile:
//   P1: read aLo(8)+bLo(4);           BAR lgkm0 prio MFMA(Q1: mt0-3 x nt0-1) BAR
//   P2: read bHi(4);                  BAR lgkm0 prio MFMA(Q2: mt0-3 x nt2-3) BAR
//   P3: read aHi(8) + stage B(t+2);   BAR lgkm0 prio MFMA(Q3: mt4-7 x nt2-3) BAR
//   P4: stage A(t+2) + vmcnt(8);      BAR       prio MFMA(Q4: mt4-7 x nt0-1) BAR
// bLo is register-held P1->P4. Stage of region R happens >= 1 barrier after
// R's last ds_read (B last read P2, staged P3; A last read P3, staged P4).
// vmcnt(8) at P4 leaves exactly tile t+2's 8 loads in flight -> tile t+1
// fully landed before its P1 (collective via BAR). Never 0 in main loop.
// LDS swizzle: phys_col = col ^ ((row&7)<<4) on 128B rows (bandwidth-minimum
// bank spread, round-2-verified mechanics); linear gload_lds dest +
// inverse-swizzled global source (both-sides rule).
// ============================================================================
__global__ __launch_bounds__(512, 2) void gemm8p(const bf16_t* __restrict__ A,
                                                 const bf16_t* __restrict__ B,
                                                 const float* __restrict__ alpha_p,
                                                 float* __restrict__ C) {
  extern __shared__ char smem[];  // buf(t&1): A @ tb+0 (32KB), B @ tb+32768

  const int tid = threadIdx.x;
  const int lane = tid & 63;
  const int wid = tid >> 6;
  const int wm = wid >> 2;   // 0..1 -> rows wm*128..+127
  const int wn = wid & 3;    // 0..3 -> cols wn*64..+63

  // XCD-aware bijective swizzle (512 blocks, 512 % 8 == 0)
  const int bid = blockIdx.x;
  const int swz = (bid & 7) * 64 + (bid >> 3);
  const int bm = swz >> 3;   // 0..63
  const int bn = swz & 7;    // 0..7

  const int q = lane >> 4;   // 16B col-slot within K
  const int r15 = lane & 15; // frag row

  // ---- Fragment LDS byte bases (add TB + mt*2048 / nt*2048 immediates) ----
  // addr(row=*+mt*16+r15, k) = row*128 + ((k*64+q*16) ^ ((r15&7)<<4))
  const int swc = (r15 & 7) << 4;
  int aoff[2], boff[2];
#pragma unroll
  for (int k = 0; k < 2; ++k) {
    int ck = (k * 64 + q * 16) ^ swc;
    aoff[k] = (wm * 128 + r15) * 128 + ck;
    boff[k] = 32768 + (wn * 64 + r15) * 128 + ck;
  }

  // ---- Stage pointers (tile 0): inverse-swizzled global src, linear dest ----
  const char* asrc[4];
  const char* bsrc[4];
  int adsto[4], bdsto[4];
#pragma unroll
  for (int j = 0; j < 4; ++j) {
    int P = j * 8192 + tid * 16;                 // phys byte in 32KB tile
    int row = P >> 7;                            // 0..255
    int lcol = (P & 127) ^ ((row & 7) << 4);     // logical K-byte in row
    asrc[j] = (const char*)A + (size_t)(bm * 256 + row) * (K_DIM * 2) + lcol;
    bsrc[j] = (const char*)B + (size_t)(bn * 256 + row) * (K_DIM * 2) + lcol;
    adsto[j] = j * 8192 + wid * 1024;            // wave-uniform linear dest
    bdsto[j] = 32768 + j * 8192 + wid * 1024;
  }

  f32x4 acc[8][4];
#pragma unroll
  for (int mt = 0; mt < 8; ++mt)
#pragma unroll
    for (int nt = 0; nt < 4; ++nt) acc[mt][nt] = (f32x4){0.f, 0.f, 0.f, 0.f};

  // ---- Prologue: stage tiles 0,1 (16 loads); wait tile 0 (8 younger) ----
#pragma unroll
  for (int t = 0; t < 2; ++t) {
#pragma unroll
    for (int j = 0; j < 4; ++j)
      gload_lds16(asrc[j] + t * 128, smem + t * 65536 + adsto[j]);
#pragma unroll
    for (int j = 0; j < 4; ++j)
      gload_lds16(bsrc[j] + t * 128, smem + t * 65536 + bdsto[j]);
  }
  asm volatile("s_waitcnt vmcnt(8)" ::: "memory");
  __builtin_amdgcn_s_barrier();

  // One K-tile (BK=64, 4 phases). U = t&1. MODE: 0 = stage t+2 + vmcnt(8);
  // 1 = no stage, vmcnt(0) (t=30); 2 = no stage, no vmcnt (t=31).
  auto kstep = [&](auto UC, auto MC) {
    constexpr int U = UC.value;
    constexpr int MODE = MC.value;
    constexpr int TB = U * 65536;
    constexpr int GOFF = (U + 2) * 128;

    bf16x8 a[4][2], bL[2][2], bH[2][2];

    // ---- P1: read aLo(8) + bLo(4); MFMA Q1 = mt0-3 x nt0-1 ----
#pragma unroll
    for (int mt = 0; mt < 4; ++mt)
#pragma unroll
      for (int k = 0; k < 2; ++k)
        a[mt][k] = *(const bf16x8*)(smem + TB + aoff[k] + mt * 2048);
#pragma unroll
    for (int nt = 0; nt < 2; ++nt)
#pragma unroll
      for (int k = 0; k < 2; ++k)
        bL[nt][k] = *(const bf16x8*)(smem + TB + boff[k] + nt * 2048);
    __builtin_amdgcn_s_barrier();
    asm volatile("s_waitcnt lgkmcnt(0)" ::: "memory");
    __builtin_amdgcn_s_setprio(1);
#pragma unroll
    for (int k = 0; k < 2; ++k)
#pragma unroll
      for (int mt = 0; mt < 4; ++mt)
#pragma unroll
        for (int nt = 0; nt < 2; ++nt)
          acc[mt][nt] = __builtin_amdgcn_mfma_f32_16x16x32_bf16(
              a[mt][k], bL[nt][k], acc[mt][nt], 0, 0, 0);
    __builtin_amdgcn_s_setprio(0);
    __builtin_amdgcn_s_barrier();

    // ---- P2: read bHi(4); MFMA Q2 = mt0-3 x nt2-3 ----
#pragma unroll
    for (int nt = 0; nt < 2; ++nt)
#pragma unroll
      for (int k = 0; k < 2; ++k)
        bH[nt][k] = *(const bf16x8*)(smem + TB + boff[k] + (2 + nt) * 2048);
    __builtin_amdgcn_s_barrier();
    asm volatile("s_waitcnt lgkmcnt(0)" ::: "memory");
    __builtin_amdgcn_s_setprio(1);
#pragma unroll
    for (int k = 0; k < 2; ++k)
#pragma unroll
      for (int mt = 0; mt < 4; ++mt)
#pragma unroll
        for (int nt = 0; nt < 2; ++nt)
          acc[mt][2 + nt] = __builtin_amdgcn_mfma_f32_16x16x32_bf16(
              a[mt][k], bH[nt][k], acc[mt][2 + nt], 0, 0, 0);
    __builtin_amdgcn_s_setprio(0);
    __builtin_amdgcn_s_barrier();

    // ---- P3: read aHi(8); stage B(t+2); MFMA Q3 = mt4-7 x nt2-3 ----
#pragma unroll
    for (int mt = 0; mt < 4; ++mt)
#pragma unroll
      for (int k = 0; k < 2; ++k)
        a[mt][k] = *(const bf16x8*)(smem + TB + aoff[k] + (4 + mt) * 2048);
    if constexpr (MODE == 0) {
#pragma unroll
      for (int j = 0; j < 4; ++j)
        gload_lds16(bsrc[j] + GOFF, smem + TB + bdsto[j]);
    }
    __builtin_amdgcn_s_barrier();
    asm volatile("s_waitcnt lgkmcnt(0)" ::: "memory");
    __builtin_amdgcn_s_setprio(1);
#pragma unroll
    for (int k = 0; k < 2; ++k)
#pragma unroll
      for (int mt = 0; mt < 4; ++mt)
#pragma unroll
        for (int nt = 0; nt < 2; ++nt)
          acc[4 + mt][2 + nt] = __builtin_amdgcn_mfma_f32_16x16x32_bf16(
              a[mt][k], bH[nt][k], acc[4 + mt][2 + nt], 0, 0, 0);
    __builtin_amdgcn_s_setprio(0);
    __builtin_amdgcn_s_barrier();

    // ---- P4: stage A(t+2); vmcnt; MFMA Q4 = mt4-7 x nt0-1 ----
    if constexpr (MODE == 0) {
#pragma unroll
      for (int j = 0; j < 4; ++j)
        gload_lds16(asrc[j] + GOFF, smem + TB + adsto[j]);
      asm volatile("s_waitcnt vmcnt(8)" ::: "memory");  // tile t+1 landed
    } else if constexpr (MODE == 1) {
      asm volatile("s_waitcnt vmcnt(0)" ::: "memory");  // tile 31 landed
    }
    __builtin_amdgcn_s_barrier();
    __builtin_amdgcn_s_setprio(1);
#pragma unroll
    for (int k = 0; k < 2; ++k)
#pragma unroll
      for (int mt = 0; mt < 4; ++mt)
#pragma unroll
        for (int nt = 0; nt < 2; ++nt)
          acc[4 + mt][nt] = __builtin_amdgcn_mfma_f32_16x16x32_bf16(
              a[mt][k], bL[nt][k], acc[4 + mt][nt], 0, 0, 0);
    __builtin_amdgcn_s_setprio(0);
    __builtin_amdgcn_s_barrier();
  };

#pragma unroll 1
  for (int T = 0; T < 15; ++T) {
    kstep(ic<0>{}, ic<0>{});
    kstep(ic<1>{}, ic<0>{});
#pragma unroll
    for (int j = 0; j < 4; ++j) { asrc[j] += 256; bsrc[j] += 256; }
  }
  kstep(ic<0>{}, ic<1>{});   // t=30: no stage, vmcnt(0)
  kstep(ic<1>{}, ic<2>{});   // t=31: no stage, no vmcnt

  // ---- Epilogue: 16x16 C/D layout col=lane&15, row=(lane>>4)*4+reg ----
  const float alpha = alpha_p[0];
  const int rbase = bm * 256 + wm * 128 + q * 4;
  const int cbase = bn * 256 + wn * 64 + r15;
#pragma unroll
  for (int mt = 0; mt < 8; ++mt)
#pragma unroll
    for (int nt = 0; nt < 4; ++nt)
#pragma unroll
      for (int r = 0; r < 4; ++r)
        C[(size_t)(rbase + mt * 16 + r) * N_DIM + cbase + nt * 16] =
            alpha * acc[mt][nt][r];
}

// ---- Workspace-free fallback (round-1 verified structure, f32 reg-staged) ----
__global__ __launch_bounds__(256) void gemm_fallback(const float* __restrict__ Ap,
                                                     const float* __restrict__ Bp,
                                                     const float* __restrict__ alpha_p,
                                                     float* __restrict__ C) {
  __shared__ bf16_t Asf[128 * 32];
  __shared__ bf16_t Bsf[128 * 32];
  const int tid = threadIdx.x;
  const int lane = tid & 63;
  const int wid = tid >> 6;
  const int wr = wid >> 1;
  const int wc = wid & 1;
  const int cpx = gridDim.x >> 3;
  const int bid = blockIdx.x;
  const int swz = (bid & 7) * cpx + (bid >> 3);
  const int NB = N_DIM / 128;
  const int bm = swz / NB;
  const int bn = swz % NB;
  f32x4 acc[4][4];
#pragma unroll
  for (int m = 0; m < 4; ++m)
#pragma unroll
    for (int n = 0; n < 4; ++n) acc[m][n] = (f32x4){0.f, 0.f, 0.f, 0.f};
  const int r0 = lane & 15;
  const int ko = (lane >> 4) * 8;
  for (int kk = 0; kk < K_DIM; kk += 32) {
    const float* Af = Ap + (size_t)bm * 128 * K_DIM + kk;
    const float* Bf = Bp + (size_t)bn * 128 * K_DIM + kk;
#pragma unroll
    for (int qq = 0; qq < 4; ++qq) {
      int e = qq * 256 + tid;
      int row = e >> 3;
      int kc = (e & 7) << 2;
      float4 v = *(const float4*)(Af + (size_t)row * K_DIM + kc);
      bf16x4 tv;
      tv[0] = (bf16_t)v.x; tv[1] = (bf16_t)v.y; tv[2] = (bf16_t)v.z; tv[3] = (bf16_t)v.w;
      *(bf16x4*)&Asf[e * 4] = tv;
    }
#pragma unroll
    for (int qq = 0; qq < 4; ++qq) {
      int e = qq * 256 + tid;
      int row = e >> 3;
      int kc = (e & 7) << 2;
      float4 v = *(const float4*)(Bf + (size_t)row * K_DIM + kc);
      float s[4] = {v.x, v.y, v.z, v.w};
      bf16x4 tv;
#pragma unroll
      for (int j = 0; j < 4; ++j)
        tv[j] = (bf16_t)((s[j] > 0.f) ? 1.f : ((s[j] < 0.f) ? -1.f : 0.f));
      *(bf16x4*)&Bsf[e * 4] = tv;
    }
    __syncthreads();
    bf16x8 a[4], b[4];
#pragma unroll
    for (int m = 0; m < 4; ++m) a[m] = *(const bf16x8*)&Asf[(wr * 64 + m * 16 + r0) * 32 + ko];
#pragma unroll
    for (int n = 0; n < 4; ++n) b[n] = *(const bf16x8*)&Bsf[(wc * 64 + n * 16 + r0) * 32 + ko];
#pragma unroll
    for (int m = 0; m < 4; ++m)
#pragma unroll
      for (int n = 0; n < 4; ++n)
        acc[m][n] = __builtin_amdgcn_mfma_f32_16x16x32_bf16(a[m], b[n], acc[m][n], 0, 0, 0);
    __syncthreads();
  }
  const float alpha = alpha_p[0];
  const int rowb = bm * 128 + wr * 64 + (lane >> 4) * 4;
  const int colb = bn * 128 + wc * 64 + r0;
#pragma unroll
  for (int m = 0; m < 4; ++m)
#pragma unroll
    for (int n = 0; n < 4; ++n)
#pragma unroll
      for (int r = 0; r < 4; ++r)
        C[(size_t)(rowb + m * 16 + r) * N_DIM + colb + n * 16] = alpha * acc[m][n][r];
}

extern "C" void kernel_launch(void* const* d_in, const int* in_sizes, int n_in,
                              void* d_out, int out_size, void* d_ws, size_t ws_size,
                              hipStream_t stream) {
  const float* x = (const float*)d_in[0];
  const float* w = (const float*)d_in[1];
  const float* alpha = (const float*)d_in[2];
  float* out = (float*)d_out;

  const size_t nx = (size_t)M_DIM * K_DIM;
  const size_t nw = (size_t)N_DIM * K_DIM;
  const size_t need = (nx + nw) * sizeof(bf16_t);

  if (ws_size >= need) {
    bf16_t* xb = (bf16_t*)d_ws;
    bf16_t* wb = xb + nx;
    cvt_kernel<false><<<(int)(nx / 2048), 256, 0, stream>>>(x, xb);
    cvt_kernel<true><<<(int)(nw / 2048), 256, 0, stream>>>(w, wb);
    (void)hipFuncSetAttribute((const void*)gemm8p,
                              hipFuncAttributeMaxDynamicSharedMemorySize, 131072);
    gemm8p<<<512, 512, 131072, stream>>>(xb, wb, alpha, out);
  } else {
    gemm_fallback<<<(M_DIM / 128) * (N_DIM / 128), 256, 0, stream>>>(x, w, alpha, out);
  }
}